// Round 5
// baseline (164.101 us; speedup 1.0000x reference)
//
#include <hip/hip_runtime.h>
#include <hip/hip_bf16.h>

typedef __attribute__((ext_vector_type(8))) short short8;
typedef __attribute__((ext_vector_type(4))) float float4v;

#define T_LEN 4096
#define L_LEN 128
#define NWIN  3969
#define CK    128
#define W_BLK 128
#define NSPLIT 4
#define NCHUNK_B 8

// ws layout: [wsB 32KB][csum 512B]   (33 KB total — proven safe)
#define CSUM_OFF  32768

__device__ __forceinline__ unsigned short f2bf(float f) {
    unsigned u = __float_as_uint(f);
    u += 0x7fffu + ((u >> 16) & 1u);          // RNE
    return (unsigned short)(u >> 16);
}
__device__ __forceinline__ float bf2f(unsigned short b) {
    return __uint_as_float(((unsigned)b) << 16);
}
__device__ __forceinline__ int chunkT0(int c) {
    return (c < 31) ? c * W_BLK : (NWIN - W_BLK);   // last chunk overlaps
}

// grid 256 x 128 threads: blocks 0..127 zero-init d_out (positive-float max
// floor); blocks 128..255 normalize shapelet ck and write B-swizzled bf16.
__global__ void prep_init(const float* __restrict__ sh,
                          unsigned short* __restrict__ wsB,
                          float* __restrict__ csum,
                          unsigned* __restrict__ oenc) {
    const int t = threadIdx.x;           // 128 threads
    if (blockIdx.x < 128) {
        oenc[blockIdx.x * 256 + t]       = 0u;   // +0.0f floor
        oenc[blockIdx.x * 256 + 128 + t] = 0u;
        return;
    }
    const int ck = blockIdx.x - 128;
    const int l  = t;
    __shared__ float rs[2], rq[2], rc[2];
    const int lane = t & 63, wv = t >> 6;

    float v = sh[ck * L_LEN + l];
    float s = v, q = v * v;
    #pragma unroll
    for (int off = 32; off >= 1; off >>= 1) {
        s += __shfl_xor(s, off);
        q += __shfl_xor(q, off);
    }
    if (lane == 0) { rs[wv] = s; rq[wv] = q; }
    __syncthreads();
    float sm = rs[0] + rs[1], sq = rq[0] + rq[1];
    float mu  = sm * (1.f / L_LEN);
    float var = fmaxf(sq * (1.f / L_LEN) - mu * mu, 0.f);
    float inv = 1.f / (sqrtf(var) + 1e-6f);

    unsigned short b = f2bf((v - mu) * inv);
    // B-operand fragment order: lane' = qd*16 + n, 8 contiguous bf16
    const int nt = ck >> 4, n = ck & 15;
    const int kt = l >> 5, qd = (l >> 3) & 3, jj = l & 7;
    wsB[((((nt * 4 + kt) * 64) + qd * 16 + n) << 3) + jj] = b;

    float cv = bf2f(b);
    #pragma unroll
    for (int off = 32; off >= 1; off >>= 1) cv += __shfl_xor(cv, off);
    if (lane == 0) rc[wv] = cv;
    __syncthreads();
    if (t == 0) csum[ck] = rc[0] + rc[1];
}

// block = (row, split of 8 chunks); 4 waves; loops chunks with x-prefetch.
// B read from global in K-loop (L1-resident, off the LDS pipe).
__global__ __launch_bounds__(256, 4)
void conv_main(const float* __restrict__ x,
               const unsigned short* __restrict__ wsB,
               const float* __restrict__ csum,
               unsigned* __restrict__ oenc) {
    __shared__ alignas(16) unsigned short xb[8][256]; // 8 shifted bf16 copies
    __shared__ float PS[257], PQ[257];
    __shared__ float wts[4], wtq[4];
    __shared__ float2 st[W_BLK];
    __shared__ float wmax[4][64];

    const int tid   = threadIdx.x;
    const int lane  = tid & 63;
    const int wv    = tid >> 6;
    const int row   = blockIdx.x >> 2;        // 0..255
    const int split = blockIdx.x & 3;         // 0..3
    const int c0    = split * NCHUNK_B;

    const int nhalf  = wv & 1;
    const int mgroup = wv >> 1;
    const int abase  = (lane & 15) + (lane >> 4);

    float cck[4];
    #pragma unroll
    for (int nt4 = 0; nt4 < 4; ++nt4)
        cck[nt4] = csum[(nhalf * 4 + nt4) * 16 + (lane & 15)];

    float vmax[4] = {-1e30f, -1e30f, -1e30f, -1e30f};
    const int q4 = (lane >> 4) * 4;
    const short8* Bp = (const short8*)wsB;

    // prefetch chunk 0's x element
    float pv = 0.f;
    if (tid < 255) pv = x[row * T_LEN + chunkT0(c0) + tid];

    for (int i = 0; i < NCHUNK_B; ++i) {
        float v = pv;
        if (i + 1 < NCHUNK_B) {
            pv = 0.f;
            if (tid < 255) pv = x[row * T_LEN + chunkT0(c0 + i + 1) + tid];
        }

        // ---- stage 8 shifted bf16 copies (xb free since prev b3) ----
        if (tid < 255) {
            unsigned short b = f2bf(v);
            #pragma unroll
            for (int c8 = 0; c8 < 8; ++c8) {
                int ii = tid - c8;
                if (ii >= 0) xb[c8][ii] = b;
            }
        }

        // ---- parallel scan of (v, v^2) ----
        float s = v, q = v * v;
        #pragma unroll
        for (int off = 1; off < 64; off <<= 1) {
            float ts = __shfl_up(s, off);
            float tq = __shfl_up(q, off);
            if (lane >= off) { s += ts; q += tq; }
        }
        if (lane == 63) { wts[wv] = s; wtq[wv] = q; }
        __syncthreads();                       // b1: xb + wave totals
        float os = 0.f, oq = 0.f;
        #pragma unroll
        for (int w = 0; w < 3; ++w) if (w < wv) { os += wts[w]; oq += wtq[w]; }
        PS[tid + 1] = os + s;
        PQ[tid + 1] = oq + q;
        if (tid == 0) { PS[0] = 0.f; PQ[0] = 0.f; }
        __syncthreads();                       // b2: PS/PQ ready

        if (tid < W_BLK) {
            float S  = PS[tid + L_LEN] - PS[tid];
            float Q  = PQ[tid + L_LEN] - PQ[tid];
            float mu = S * (1.f / L_LEN);
            float var = fmaxf(Q * (1.f / L_LEN) - mu * mu, 0.f);
            float sd  = sqrtf(var) + 1e-6f;
            st[tid] = make_float2(mu, 1.f / (sd * (float)L_LEN));
        }

        // ---- MFMA K-loop (independent of st; hides the st write) ----
        float4v acc[4][4];
        #pragma unroll
        for (int a = 0; a < 4; ++a)
            #pragma unroll
            for (int b = 0; b < 4; ++b)
                acc[a][b] = float4v{0.f, 0.f, 0.f, 0.f};

        #pragma unroll
        for (int kt = 0; kt < 4; ++kt) {
            short8 bq[4];                       // streamed: 16 live regs
            #pragma unroll
            for (int nt4 = 0; nt4 < 4; ++nt4)
                bq[nt4] = Bp[((nhalf * 4 + nt4) * 4 + kt) * 64 + lane];
            #pragma unroll
            for (int mi = 0; mi < 4; ++mi) {
                int j = mgroup * 4 + mi;
                short8 af = *(const short8*)&xb[j][8 * (abase + 4 * kt)];
                #pragma unroll
                for (int nt4 = 0; nt4 < 4; ++nt4)
                    acc[mi][nt4] = __builtin_amdgcn_mfma_f32_16x16x32_bf16(
                        af, bq[nt4], acc[mi][nt4], 0, 0, 0);
            }
        }
        __syncthreads();                       // b3: st ready, xb consumed

        // ---- epilogue: normalize + running max ----
        #pragma unroll
        for (int mi = 0; mi < 4; ++mi) {
            int j = mgroup * 4 + mi;
            #pragma unroll
            for (int r = 0; r < 4; ++r) {
                float2 s2 = st[j + 8 * (q4 + r)];
                #pragma unroll
                for (int nt4 = 0; nt4 < 4; ++nt4) {
                    float corr = (acc[mi][nt4][r] - s2.x * cck[nt4]) * s2.y;
                    vmax[nt4] = fmaxf(vmax[nt4], corr);
                }
            }
        }
    }

    // ---- block-level combine + one atomic set per block ----
    #pragma unroll
    for (int nt4 = 0; nt4 < 4; ++nt4) {
        float vx = vmax[nt4];
        vx = fmaxf(vx, __shfl_xor(vx, 16));
        vx = fmaxf(vx, __shfl_xor(vx, 32));
        if (lane < 16) wmax[wv][nt4 * 16 + lane] = vx;
    }
    __syncthreads();
    if (tid < 128) {
        int ck = tid;
        int nh = ck >> 6, idx = ck & 63;
        float vx = fmaxf(wmax[nh][idx], wmax[nh + 2][idx]);
        vx = fmaxf(vx, 0.f);   // outputs >=0 w.h.p.; keeps uint-max ordering
        atomicMax(&oenc[row * CK + ck], __float_as_uint(vx));
    }
}

extern "C" void kernel_launch(void* const* d_in, const int* in_sizes, int n_in,
                              void* d_out, int out_size, void* d_ws, size_t ws_size,
                              hipStream_t stream) {
    (void)in_sizes; (void)n_in; (void)out_size; (void)ws_size;
    const float* x  = (const float*)d_in[0];
    const float* sh = (const float*)d_in[1];
    unsigned short* wsB = (unsigned short*)d_ws;
    float* csum = (float*)((char*)d_ws + CSUM_OFF);
    unsigned* oenc = (unsigned*)d_out;   // positive-float bit patterns

    prep_init<<<256, 128, 0, stream>>>(sh, wsB, csum, oenc);
    conv_main<<<256 * NSPLIT, 256, 0, stream>>>(x, wsB, csum, oenc);
}

// Round 6
// 124.497 us; speedup vs baseline: 1.3181x; 1.3181x over previous
//
#include <hip/hip_runtime.h>
#include <hip/hip_bf16.h>

typedef __attribute__((ext_vector_type(8))) short short8;
typedef __attribute__((ext_vector_type(4))) float float4v;

#define T_LEN 4096
#define L_LEN 128
#define NWIN  3969
#define CK    128
#define NSPLIT 4
#define NCH    8                 // chunks per block
#define SPAN   1168              // staged elems per split (need 1151)
#define NSLOT  292               // SPAN/4 float4 slots
#define XBS    1168              // xb row stride (elems), 16B-multiple

// ws layout: [wsB 32KB][csum 512B]  (33 KB — proven safe)
#define CSUM_OFF 32768

// padded stats index (float2): w and w+32 land on different banks
#define STIX(w) ((w) + ((w) >> 5))

__device__ __forceinline__ unsigned short f2bf(float f) {
    unsigned u = __float_as_uint(f);
    u += 0x7fffu + ((u >> 16) & 1u);          // RNE
    return (unsigned short)(u >> 16);
}
__device__ __forceinline__ float bf2f(unsigned short b) {
    return __uint_as_float(((unsigned)b) << 16);
}

// grid 256 x 128: blocks 0..127 zero-init d_out; 128..255 normalize shapelets
__global__ void prep_init(const float* __restrict__ sh,
                          unsigned short* __restrict__ wsB,
                          float* __restrict__ csum,
                          unsigned* __restrict__ oenc) {
    const int t = threadIdx.x;
    if (blockIdx.x < 128) {
        oenc[blockIdx.x * 256 + t]       = 0u;   // +0.0f floor
        oenc[blockIdx.x * 256 + 128 + t] = 0u;
        return;
    }
    const int ck = blockIdx.x - 128;
    const int l  = t;
    __shared__ float rs[2], rq[2], rc[2];
    const int lane = t & 63, wv = t >> 6;

    float v = sh[ck * L_LEN + l];
    float s = v, q = v * v;
    #pragma unroll
    for (int off = 32; off >= 1; off >>= 1) {
        s += __shfl_xor(s, off);
        q += __shfl_xor(q, off);
    }
    if (lane == 0) { rs[wv] = s; rq[wv] = q; }
    __syncthreads();
    float sm = rs[0] + rs[1], sq = rq[0] + rq[1];
    float mu  = sm * (1.f / L_LEN);
    float var = fmaxf(sq * (1.f / L_LEN) - mu * mu, 0.f);
    float inv = 1.f / (sqrtf(var) + 1e-6f);

    unsigned short b = f2bf((v - mu) * inv);
    const int nt = ck >> 4, n = ck & 15;
    const int kt = l >> 5, qd = (l >> 3) & 3, jj = l & 7;
    wsB[((((nt * 4 + kt) * 64) + qd * 16 + n) << 3) + jj] = b;

    float cv = bf2f(b);
    #pragma unroll
    for (int off = 32; off >= 1; off >>= 1) cv += __shfl_xor(cv, off);
    if (lane == 0) rc[wv] = cv;
    __syncthreads();
    if (t == 0) csum[ck] = rc[0] + rc[1];
}

// block = (row, split of 8 chunks); 4 waves; preamble once, then a
// barrier-free chunk loop of pure ds_read/MFMA/epilogue.
__global__ __launch_bounds__(256, 4)
void conv_main(const float* __restrict__ x,
               const unsigned short* __restrict__ wsB,
               const float* __restrict__ csum,
               unsigned* __restrict__ oenc) {
    __shared__ alignas(16) unsigned short xbL[8 * XBS];   // 18688 B
    __shared__ alignas(16) float xf[SPAN];                // 4672 B
    __shared__ float2 stP[1024 + 32];                     // 8448 B
    __shared__ float segS[NSLOT], segQ[NSLOT];            // 2336 B
    __shared__ float grpS[64], grpQ[64];                  // 512 B
    __shared__ float wmax[4][64];                         // 1024 B

    const int tid   = threadIdx.x;
    const int lane  = tid & 63;
    const int wv    = tid >> 6;
    const int row   = blockIdx.x >> 2;
    const int split = blockIdx.x & 3;
    const int S     = split << 10;
    const int c0    = split * NCH;

    // ---- stage x span: fp32 + 8 shifted bf16 copies + per-slot sums ----
    for (int f = tid; f < NSLOT; f += 256) {
        int g = S + 4 * f;
        float4 v4 = make_float4(0.f, 0.f, 0.f, 0.f);
        if (g + 3 < T_LEN) v4 = *(const float4*)(x + row * T_LEN + g);
        ((float4*)xf)[f] = v4;
        float vv[4] = {v4.x, v4.y, v4.z, v4.w};
        float s = 0.f, q = 0.f;
        #pragma unroll
        for (int e = 0; e < 4; ++e) {
            int el = 4 * f + e;
            unsigned short b = f2bf(vv[e]);
            s += vv[e]; q += vv[e] * vv[e];
            #pragma unroll
            for (int c = 0; c < 8; ++c) {
                int idx = el - c;
                if (idx >= 0) xbL[c * XBS + idx] = b;
            }
        }
        segS[f] = s; segQ[f] = q;
    }
    __syncthreads();

    // ---- 37 groups of 8 slots -> sums -> wave-0 exclusive scan ----
    if (tid < 37) {
        float s = 0.f, q = 0.f;
        #pragma unroll
        for (int k = 0; k < 8; ++k) {
            int f = tid * 8 + k;
            if (f < NSLOT) { s += segS[f]; q += segQ[f]; }
        }
        grpS[tid] = s; grpQ[tid] = q;
    }
    __syncthreads();
    if (tid < 64) {
        float s = (tid < 37) ? grpS[tid] : 0.f;
        float q = (tid < 37) ? grpQ[tid] : 0.f;
        float s0 = s, q0 = q;
        #pragma unroll
        for (int off = 1; off < 64; off <<= 1) {
            float ts = __shfl_up(s, off);
            float tq = __shfl_up(q, off);
            if (lane >= off) { s += ts; q += tq; }
        }
        if (tid < 37) { grpS[tid] = s - s0; grpQ[tid] = q - q0; }  // exclusive
    }
    __syncthreads();

    // ---- window stats: thread t -> windows 4t..4t+3 (all w < 1024) ----
    {
        const int t = tid;
        float Pa_s = grpS[t >> 3], Pa_q = grpQ[t >> 3];
        for (int f = (t & ~7); f < t; ++f) { Pa_s += segS[f]; Pa_q += segQ[f]; }
        const int t2 = t + 32;
        float Pb_s = grpS[t2 >> 3], Pb_q = grpQ[t2 >> 3];
        for (int f = (t2 & ~7); f < t2; ++f) { Pb_s += segS[f]; Pb_q += segQ[f]; }
        float Ssum = Pb_s - Pa_s;                 // sum over [4t, 4t+128)
        float Qsum = Pb_q - Pa_q;
        float4 vf = ((const float4*)xf)[t];
        float4 vl = ((const float4*)xf)[t + 32];
        float fs[4] = {vf.x, vf.y, vf.z, vf.w};
        float ls[4] = {vl.x, vl.y, vl.z, vl.w};
        #pragma unroll
        for (int e = 0; e < 4; ++e) {
            int w = 4 * t + e;
            float mu  = Ssum * (1.f / L_LEN);
            float var = fmaxf(Qsum * (1.f / L_LEN) - mu * mu, 0.f);
            float sd  = sqrtf(var) + 1e-6f;
            stP[STIX(w)] = make_float2(mu, 1.f / (sd * (float)L_LEN));
            if (e < 3) {
                Ssum += ls[e] - fs[e];
                Qsum = Qsum + ls[e] * ls[e] - fs[e] * fs[e];
            }
        }
    }
    __syncthreads();                       // xbL + stP ready for all waves

    // ---- barrier-free chunk loop ----
    const int nhalf  = wv & 1;
    const int mgroup = wv >> 1;
    const int abase  = (lane & 15) + (lane >> 4);
    const int q4     = (lane >> 4) * 4;
    const short8* Bp = (const short8*)wsB;

    float cck[4];
    #pragma unroll
    for (int nt4 = 0; nt4 < 4; ++nt4)
        cck[nt4] = csum[(nhalf * 4 + nt4) * 16 + (lane & 15)];

    float vmax[4] = {-1e30f, -1e30f, -1e30f, -1e30f};

    for (int i = 0; i < NCH; ++i) {
        const int ci  = c0 + i;
        const int T0l = ((ci < 31) ? ci * 128 : (NWIN - 128)) - S;

        int cI[4], b8[4];
        #pragma unroll
        for (int mi = 0; mi < 4; ++mi) {
            int e0 = T0l + mgroup * 4 + mi;
            cI[mi] = e0 & 7;
            b8[mi] = (e0 - cI[mi]) >> 3;
        }

        float4v acc[4][4];
        #pragma unroll
        for (int a = 0; a < 4; ++a)
            #pragma unroll
            for (int b = 0; b < 4; ++b)
                acc[a][b] = float4v{0.f, 0.f, 0.f, 0.f};

        #pragma unroll
        for (int kt = 0; kt < 4; ++kt) {
            short8 bq[4];
            #pragma unroll
            for (int nt4 = 0; nt4 < 4; ++nt4)
                bq[nt4] = Bp[((nhalf * 4 + nt4) * 4 + kt) * 64 + lane];
            #pragma unroll
            for (int mi = 0; mi < 4; ++mi) {
                const short8 af = *(const short8*)
                    &xbL[cI[mi] * XBS + 8 * (b8[mi] + abase + 4 * kt)];
                #pragma unroll
                for (int nt4 = 0; nt4 < 4; ++nt4)
                    acc[mi][nt4] = __builtin_amdgcn_mfma_f32_16x16x32_bf16(
                        af, bq[nt4], acc[mi][nt4], 0, 0, 0);
            }
        }

        #pragma unroll
        for (int mi = 0; mi < 4; ++mi) {
            int j = mgroup * 4 + mi;
            #pragma unroll
            for (int r = 0; r < 4; ++r) {
                int w = T0l + j + 8 * (q4 + r);
                float2 s2 = stP[STIX(w)];
                #pragma unroll
                for (int nt4 = 0; nt4 < 4; ++nt4) {
                    float corr = (acc[mi][nt4][r] - s2.x * cck[nt4]) * s2.y;
                    vmax[nt4] = fmaxf(vmax[nt4], corr);
                }
            }
        }
    }

    // ---- block combine + one atomic per ck per block ----
    #pragma unroll
    for (int nt4 = 0; nt4 < 4; ++nt4) {
        float vx = vmax[nt4];
        vx = fmaxf(vx, __shfl_xor(vx, 16));
        vx = fmaxf(vx, __shfl_xor(vx, 32));
        if (lane < 16) wmax[wv][nt4 * 16 + lane] = vx;
    }
    __syncthreads();
    if (tid < 128) {
        int ck = tid;
        int nh = ck >> 6, idx = ck & 63;
        float vx = fmaxf(wmax[nh][idx], wmax[nh + 2][idx]);
        vx = fmaxf(vx, 0.f);   // outputs >=0 w.h.p.; keeps uint-max ordering
        atomicMax(&oenc[row * CK + ck], __float_as_uint(vx));
    }
}

extern "C" void kernel_launch(void* const* d_in, const int* in_sizes, int n_in,
                              void* d_out, int out_size, void* d_ws, size_t ws_size,
                              hipStream_t stream) {
    (void)in_sizes; (void)n_in; (void)out_size; (void)ws_size;
    const float* x  = (const float*)d_in[0];
    const float* sh = (const float*)d_in[1];
    unsigned short* wsB = (unsigned short*)d_ws;
    float* csum = (float*)((char*)d_ws + CSUM_OFF);
    unsigned* oenc = (unsigned*)d_out;   // positive-float bit patterns

    prep_init<<<256, 128, 0, stream>>>(sh, wsB, csum, oenc);
    conv_main<<<256 * NSPLIT, 256, 0, stream>>>(x, wsB, csum, oenc);
}

// Round 7
// 83.016 us; speedup vs baseline: 1.9767x; 1.4997x over previous
//
#include <hip/hip_runtime.h>
#include <hip/hip_bf16.h>

typedef __attribute__((ext_vector_type(8))) short short8;
typedef __attribute__((ext_vector_type(4))) float float4v;

#define T_LEN 4096
#define L_LEN 128
#define NWIN  3969
#define CK    128

__device__ __forceinline__ unsigned short f2bf(float f) {
    unsigned u = __float_as_uint(f);
    u += 0x7fffu + ((u >> 16) & 1u);          // RNE
    return (unsigned short)(u >> 16);
}

// 128 blocks x 128 threads: normalize shapelet ck=blockIdx, write B-swizzled
__global__ void prep_sh(const float* __restrict__ sh,
                        unsigned short* __restrict__ wsB) {
    const int ck = blockIdx.x;       // 0..127
    const int l  = threadIdx.x;      // 0..127
    __shared__ float rs[2], rq[2];
    const int lane = l & 63, wv = l >> 6;

    float v = sh[ck * L_LEN + l];
    float s = v, q = v * v;
    #pragma unroll
    for (int off = 32; off >= 1; off >>= 1) {
        s += __shfl_xor(s, off);
        q += __shfl_xor(q, off);
    }
    if (lane == 0) { rs[wv] = s; rq[wv] = q; }
    __syncthreads();
    float sm = rs[0] + rs[1], sq = rq[0] + rq[1];
    float mu  = sm * (1.f / L_LEN);
    float var = fmaxf(sq * (1.f / L_LEN) - mu * mu, 0.f);
    float inv = 1.f / (sqrtf(var) + 1e-6f);
    unsigned short b = f2bf((v - mu) * inv);
    // B-operand fragment order: lane' = qd*16 + n, 8 contiguous bf16
    const int nt = ck >> 4, n = ck & 15;
    const int kt = l >> 5, qd = (l >> 3) & 3, jj = l & 7;
    wsB[((((nt * 4 + kt) * 64) + qd * 16 + n) << 3) + jj] = b;
}

// one block per row; 512 threads = 8 waves; 1 block/CU (90 KB LDS) so the
// VGPR budget is 256: B fragments live in 128 registers for the whole row.
// wave w handles windows T0 + w + 8m (m=0..15) of every chunk -> its A-frag
// is one aligned ds_read_b128 from shifted copy (T0+w)&7.
__global__ __launch_bounds__(512, 2)
void conv_row(const float* __restrict__ x,
              const unsigned short* __restrict__ wsB,
              float* __restrict__ out) {
    __shared__ alignas(16) unsigned short xb[8][T_LEN]; // 64 KB shifted copies
    __shared__ float sty[T_LEN];                        // 16 KB: 1/(sd*L)
    __shared__ float PSs[513], PQs[513];                // prefix sums @8-elem
    __shared__ float grpS[8], grpQ[8];
    __shared__ float wmax[8][CK];                       // 4 KB

    const int tid  = threadIdx.x;
    const int lane = tid & 63;
    const int wv   = tid >> 6;
    const int row  = blockIdx.x;
    const float4* xr4 = (const float4*)(x + row * T_LEN);

    // ---- B fragments -> 128 registers (issued first: long latency) ----
    short8 Bf[8][4];
    {
        const short8* Bp = (const short8*)wsB;
        #pragma unroll
        for (int nt = 0; nt < 8; ++nt)
            #pragma unroll
            for (int kt = 0; kt < 4; ++kt)
                Bf[nt][kt] = Bp[(nt * 4 + kt) * 64 + lane];
    }

    // ---- stage row: thread t owns elems [8t,8t+8), loads 16 (overlap) ----
    float v[16];
    {
        float4 a0 = xr4[2 * tid];
        float4 a1 = xr4[2 * tid + 1];
        float4 a2 = make_float4(0.f, 0.f, 0.f, 0.f), a3 = a2;
        if (tid < 511) { a2 = xr4[2 * tid + 2]; a3 = xr4[2 * tid + 3]; }
        v[0]=a0.x; v[1]=a0.y; v[2]=a0.z;  v[3]=a0.w;
        v[4]=a1.x; v[5]=a1.y; v[6]=a1.z;  v[7]=a1.w;
        v[8]=a2.x; v[9]=a2.y; v[10]=a2.z; v[11]=a2.w;
        v[12]=a3.x; v[13]=a3.y; v[14]=a3.z; v[15]=a3.w;
    }
    unsigned short bb[16];
    #pragma unroll
    for (int i = 0; i < 16; ++i) bb[i] = f2bf(v[i]);
    #pragma unroll
    for (int c = 0; c < 8; ++c) {           // copy_c[i] = x[i+c]; aligned b128
        short8 w8;
        #pragma unroll
        for (int j = 0; j < 8; ++j) w8[j] = (short)bb[c + j];
        *(short8*)&xb[c][8 * tid] = w8;
    }

    // ---- seg sums (8 elems) + block scan -> elem-granular prefix @8 ----
    float s = 0.f, q = 0.f;
    #pragma unroll
    for (int i = 0; i < 8; ++i) { s += v[i]; q += v[i] * v[i]; }
    float is = s, iq = q;
    #pragma unroll
    for (int off = 1; off < 64; off <<= 1) {
        float ts = __shfl_up(is, off);
        float tq = __shfl_up(iq, off);
        if (lane >= off) { is += ts; iq += tq; }
    }
    if (lane == 63) { grpS[wv] = is; grpQ[wv] = iq; }
    __syncthreads();
    float os = 0.f, oq = 0.f;
    #pragma unroll
    for (int w = 0; w < 7; ++w) if (w < wv) { os += grpS[w]; oq += grpQ[w]; }
    PSs[tid] = os + is - s;                 // exclusive prefix at elem 8*tid
    PQs[tid] = oq + iq - q;
    if (tid == 511) { PSs[512] = os + is; PQs[512] = oq + iq; }
    __syncthreads();

    // ---- window stats: thread t -> windows [8t, 8t+8), incremental ----
    if (tid < 497) {
        float S = PSs[tid + 16] - PSs[tid];   // sum over [8t, 8t+128)
        float Q = PQs[tid + 16] - PQs[tid];
        float4 b0 = make_float4(0.f, 0.f, 0.f, 0.f), b1 = b0;
        if (tid <= 495) { b0 = xr4[2 * tid + 32]; b1 = xr4[2 * tid + 33]; }
        float xn[8] = {b0.x, b0.y, b0.z, b0.w, b1.x, b1.y, b1.z, b1.w};
        #pragma unroll
        for (int e = 0; e < 8; ++e) {
            int w = 8 * tid + e;
            if (w < NWIN) {
                float mu  = S * (1.f / L_LEN);
                float var = fmaxf(Q * (1.f / L_LEN) - mu * mu, 0.f);
                float sd  = sqrtf(var) + 1e-6f;
                sty[w] = 1.f / (sd * (float)L_LEN);
                S += xn[e] - v[e];
                Q += xn[e] * xn[e] - v[e] * v[e];
            }
        }
    }
    __syncthreads();                        // xb + sty ready

    // ---- chunk loop: pure ds_read_b128 + MFMA + mul/max epilogue ----
    const int abase = (lane & 15) + (lane >> 4);
    const int q4    = (lane >> 4) * 4;
    float vmax[8];
    #pragma unroll
    for (int nt = 0; nt < 8; ++nt) vmax[nt] = -1e30f;

    #pragma unroll 1                        // keep acc live-range single-iter
    for (int ci = 0; ci < 32; ++ci) {
        const int T0 = (ci < 31) ? ci * 128 : (NWIN - 128);  // last overlaps
        const int e0 = T0 + wv;
        const int c  = e0 & 7;
        const int b8 = e0 >> 3;

        float4v acc[8];
        #pragma unroll
        for (int nt = 0; nt < 8; ++nt) acc[nt] = float4v{0.f, 0.f, 0.f, 0.f};

        #pragma unroll
        for (int kt = 0; kt < 4; ++kt) {
            const short8 af = *(const short8*)&xb[c][8 * (b8 + abase + 4 * kt)];
            #pragma unroll
            for (int nt = 0; nt < 8; ++nt)
                acc[nt] = __builtin_amdgcn_mfma_f32_16x16x32_bf16(
                    af, Bf[nt][kt], acc[nt], 0, 0, 0);
        }

        // corr = acc * sty  (mu*cs correction dropped: |err| <~ 4e-4)
        #pragma unroll
        for (int r = 0; r < 4; ++r) {
            const float sr = sty[e0 + 8 * (q4 + r)];
            #pragma unroll
            for (int nt = 0; nt < 8; ++nt)
                vmax[nt] = fmaxf(vmax[nt], acc[nt][r] * sr);
        }
    }

    // ---- cross-lane + cross-wave max, direct store ----
    #pragma unroll
    for (int nt = 0; nt < 8; ++nt) {
        float vx = vmax[nt];
        vx = fmaxf(vx, __shfl_xor(vx, 16));
        vx = fmaxf(vx, __shfl_xor(vx, 32));
        if (lane < 16) wmax[wv][nt * 16 + lane] = vx;
    }
    __syncthreads();
    if (tid < CK) {
        float m = wmax[0][tid];
        #pragma unroll
        for (int w = 1; w < 8; ++w) m = fmaxf(m, wmax[w][tid]);
        out[row * CK + tid] = m;
    }
}

extern "C" void kernel_launch(void* const* d_in, const int* in_sizes, int n_in,
                              void* d_out, int out_size, void* d_ws, size_t ws_size,
                              hipStream_t stream) {
    (void)in_sizes; (void)n_in; (void)out_size; (void)ws_size;
    const float* x  = (const float*)d_in[0];
    const float* sh = (const float*)d_in[1];
    unsigned short* wsB = (unsigned short*)d_ws;   // 32 KB (proven safe)
    float* out = (float*)d_out;

    prep_sh<<<128, 128, 0, stream>>>(sh, wsB);
    conv_row<<<256, 512, 0, stream>>>(x, wsB, out);
}

// Round 8
// 82.207 us; speedup vs baseline: 1.9962x; 1.0098x over previous
//
#include <hip/hip_runtime.h>
#include <hip/hip_bf16.h>

typedef __attribute__((ext_vector_type(8))) short short8;
typedef __attribute__((ext_vector_type(4))) float float4v;

#define T_LEN 4096
#define L_LEN 128
#define NWIN  3969
#define CK    128

__device__ __forceinline__ unsigned short f2bf(float f) {
    unsigned u = __float_as_uint(f);
    u += 0x7fffu + ((u >> 16) & 1u);          // RNE
    return (unsigned short)(u >> 16);
}

// 128 blocks x 128 threads: normalize shapelet ck=blockIdx, write B-swizzled
__global__ void prep_sh(const float* __restrict__ sh,
                        unsigned short* __restrict__ wsB) {
    const int ck = blockIdx.x;       // 0..127
    const int l  = threadIdx.x;      // 0..127
    __shared__ float rs[2], rq[2];
    const int lane = l & 63, wv = l >> 6;

    float v = sh[ck * L_LEN + l];
    float s = v, q = v * v;
    #pragma unroll
    for (int off = 32; off >= 1; off >>= 1) {
        s += __shfl_xor(s, off);
        q += __shfl_xor(q, off);
    }
    if (lane == 0) { rs[wv] = s; rq[wv] = q; }
    __syncthreads();
    float sm = rs[0] + rs[1], sq = rq[0] + rq[1];
    float mu  = sm * (1.f / L_LEN);
    float var = fmaxf(sq * (1.f / L_LEN) - mu * mu, 0.f);
    float inv = 1.f / (sqrtf(var) + 1e-6f);
    unsigned short b = f2bf((v - mu) * inv);
    // B-operand fragment order: lane' = qd*16 + n, 8 contiguous bf16
    const int nt = ck >> 4, n = ck & 15;
    const int kt = l >> 5, qd = (l >> 3) & 3, jj = l & 7;
    wsB[((((nt * 4 + kt) * 64) + qd * 16 + n) << 3) + jj] = b;
}

// one block per row; 512 threads = 8 waves; 1 block/CU (90 KB LDS) so the
// VGPR budget is 256: B fragments live in 128 registers for the whole row.
// wave w handles windows T0 + w + 8m (m=0..15); chunk order is staggered per
// wave so epilogue (VALU) of one wave overlaps MFMA bursts of the others.
__global__ __launch_bounds__(512, 2)
void conv_row(const float* __restrict__ x,
              const unsigned short* __restrict__ wsB,
              float* __restrict__ out) {
    __shared__ alignas(16) unsigned short xb[8][T_LEN]; // 64 KB shifted copies
    __shared__ float sty[T_LEN];                        // 16 KB: 1/(sd*L)
    __shared__ float PSs[513], PQs[513];                // prefix sums @8-elem
    __shared__ float grpS[8], grpQ[8];
    __shared__ float wmax[8][CK];                       // 4 KB

    const int tid  = threadIdx.x;
    const int lane = tid & 63;
    const int wv   = tid >> 6;
    const int row  = blockIdx.x;
    const float4* xr4 = (const float4*)(x + row * T_LEN);

    // ---- B fragments -> 128 registers (issued first: long latency) ----
    short8 Bf[8][4];
    {
        const short8* Bp = (const short8*)wsB;
        #pragma unroll
        for (int nt = 0; nt < 8; ++nt)
            #pragma unroll
            for (int kt = 0; kt < 4; ++kt)
                Bf[nt][kt] = Bp[(nt * 4 + kt) * 64 + lane];
    }

    // ---- stage row: thread t owns elems [8t,8t+8), loads 16 (overlap) ----
    float v[16];
    {
        float4 a0 = xr4[2 * tid];
        float4 a1 = xr4[2 * tid + 1];
        float4 a2 = make_float4(0.f, 0.f, 0.f, 0.f), a3 = a2;
        if (tid < 511) { a2 = xr4[2 * tid + 2]; a3 = xr4[2 * tid + 3]; }
        v[0]=a0.x; v[1]=a0.y; v[2]=a0.z;  v[3]=a0.w;
        v[4]=a1.x; v[5]=a1.y; v[6]=a1.z;  v[7]=a1.w;
        v[8]=a2.x; v[9]=a2.y; v[10]=a2.z; v[11]=a2.w;
        v[12]=a3.x; v[13]=a3.y; v[14]=a3.z; v[15]=a3.w;
    }
    unsigned short bb[16];
    #pragma unroll
    for (int i = 0; i < 16; ++i) bb[i] = f2bf(v[i]);
    #pragma unroll
    for (int c = 0; c < 8; ++c) {           // copy_c[i] = x[i+c]; aligned b128
        short8 w8;
        #pragma unroll
        for (int j = 0; j < 8; ++j) w8[j] = (short)bb[c + j];
        *(short8*)&xb[c][8 * tid] = w8;
    }

    // ---- seg sums (8 elems) + block scan -> elem-granular prefix @8 ----
    float s = 0.f, q = 0.f;
    #pragma unroll
    for (int i = 0; i < 8; ++i) { s += v[i]; q += v[i] * v[i]; }
    float is = s, iq = q;
    #pragma unroll
    for (int off = 1; off < 64; off <<= 1) {
        float ts = __shfl_up(is, off);
        float tq = __shfl_up(iq, off);
        if (lane >= off) { is += ts; iq += tq; }
    }
    if (lane == 63) { grpS[wv] = is; grpQ[wv] = iq; }
    __syncthreads();
    float os = 0.f, oq = 0.f;
    #pragma unroll
    for (int w = 0; w < 7; ++w) if (w < wv) { os += grpS[w]; oq += grpQ[w]; }
    PSs[tid] = os + is - s;                 // exclusive prefix at elem 8*tid
    PQs[tid] = oq + iq - q;
    if (tid == 511) { PSs[512] = os + is; PQs[512] = oq + iq; }
    __syncthreads();

    // ---- window stats: thread t -> windows [8t, 8t+8), incremental ----
    if (tid < 497) {
        float S = PSs[tid + 16] - PSs[tid];   // sum over [8t, 8t+128)
        float Q = PQs[tid + 16] - PQs[tid];
        float4 b0 = make_float4(0.f, 0.f, 0.f, 0.f), b1 = b0;
        if (tid <= 495) { b0 = xr4[2 * tid + 32]; b1 = xr4[2 * tid + 33]; }
        float xn[8] = {b0.x, b0.y, b0.z, b0.w, b1.x, b1.y, b1.z, b1.w};
        #pragma unroll
        for (int e = 0; e < 8; ++e) {
            int w = 8 * tid + e;
            if (w < NWIN) {
                float mu  = S * (1.f / L_LEN);
                float var = fmaxf(Q * (1.f / L_LEN) - mu * mu, 0.f);
                float sd  = sqrtf(var) + 1e-6f;
                sty[w] = 1.f / (sd * (float)L_LEN);
                S += xn[e] - v[e];
                Q += xn[e] * xn[e] - v[e] * v[e];
            }
        }
    }
    __syncthreads();                        // xb + sty ready

    // ---- chunk loop: staggered per wave; pure ds_read_b128 + MFMA ----
    const int abase = (lane & 15) + (lane >> 4);
    const int q4    = (lane >> 4) * 4;
    float vmax[8];
    #pragma unroll
    for (int nt = 0; nt < 8; ++nt) vmax[nt] = -1e30f;

    #pragma unroll 1                        // keep acc live-range single-iter
    for (int ii = 0; ii < 32; ++ii) {
        const int ci = (ii + 4 * wv) & 31;                   // wave-staggered
        const int T0 = (ci < 31) ? ci * 128 : (NWIN - 128);  // last overlaps
        const int e0 = T0 + wv;
        const int c  = e0 & 7;
        const int b8 = e0 >> 3;

        // prefetch scale factors + all 4 A-frags up front
        float sr[4];
        #pragma unroll
        for (int r = 0; r < 4; ++r) sr[r] = sty[e0 + 8 * (q4 + r)];
        short8 af[4];
        #pragma unroll
        for (int kt = 0; kt < 4; ++kt)
            af[kt] = *(const short8*)&xb[c][8 * (b8 + abase + 4 * kt)];

        float4v acc[8];
        #pragma unroll
        for (int nt = 0; nt < 8; ++nt) acc[nt] = float4v{0.f, 0.f, 0.f, 0.f};

        #pragma unroll
        for (int kt = 0; kt < 4; ++kt)
            #pragma unroll
            for (int nt = 0; nt < 8; ++nt)
                acc[nt] = __builtin_amdgcn_mfma_f32_16x16x32_bf16(
                    af[kt], Bf[nt][kt], acc[nt], 0, 0, 0);

        // corr = acc * sty; pairwise max (max3-friendly)
        #pragma unroll
        for (int nt = 0; nt < 8; ++nt) {
            float m01 = fmaxf(acc[nt][0] * sr[0], acc[nt][1] * sr[1]);
            float m23 = fmaxf(acc[nt][2] * sr[2], acc[nt][3] * sr[3]);
            vmax[nt] = fmaxf(vmax[nt], fmaxf(m01, m23));
        }
    }

    // ---- cross-lane + cross-wave max, direct store ----
    #pragma unroll
    for (int nt = 0; nt < 8; ++nt) {
        float vx = vmax[nt];
        vx = fmaxf(vx, __shfl_xor(vx, 16));
        vx = fmaxf(vx, __shfl_xor(vx, 32));
        if (lane < 16) wmax[wv][nt * 16 + lane] = vx;
    }
    __syncthreads();
    if (tid < CK) {
        float m = wmax[0][tid];
        #pragma unroll
        for (int w = 1; w < 8; ++w) m = fmaxf(m, wmax[w][tid]);
        out[row * CK + tid] = m;
    }
}

extern "C" void kernel_launch(void* const* d_in, const int* in_sizes, int n_in,
                              void* d_out, int out_size, void* d_ws, size_t ws_size,
                              hipStream_t stream) {
    (void)in_sizes; (void)n_in; (void)out_size; (void)ws_size;
    const float* x  = (const float*)d_in[0];
    const float* sh = (const float*)d_in[1];
    unsigned short* wsB = (unsigned short*)d_ws;   // 32 KB (proven safe)
    float* out = (float*)d_out;

    prep_sh<<<128, 128, 0, stream>>>(sh, wsB);
    conv_row<<<256, 512, 0, stream>>>(x, wsB, out);
}